// Round 5
// baseline (112.802 us; speedup 1.0000x reference)
//
#include <hip/hip_runtime.h>
#include <hip/hip_cooperative_groups.h>
#include <math.h>

namespace cg = cooperative_groups;

// ---------------- workspace layout (in floats) ----------------
#define NSORT 2048
#define WS_U0   0                 // unsorted (xi, yi, conA, conB)
#define WS_U1   (NSORT*4)         // unsorted (conC, opa, depth, key)
#define WS_U2   (NSORT*8)         // unsorted (r, g, b, 0)
#define WS_UB   (NSORT*12)        // unsorted bbox (xc, yc, ex, ey); ex<0 => never contributes
#define WS_KEY  (NSORT*16)
#define WS_S0   (NSORT*17)        // depth-sorted copies
#define WS_S1   (NSORT*21)
#define WS_S2   (NSORT*25)
#define WS_SB   (NSORT*29)
#define WS_MASK (NSORT*33)        // u64 masks: ntiles x 32 words (8-byte aligned)

#define NB 256
#define NT 256
#define NWAVES (NB * NT / 64)

__device__ __forceinline__ float f_inf() { return __int_as_float(0x7f800000); }

struct GSParams {
    const float* means3D; const float* shs; const float* opacities;
    const float* scales; const float* scale_mod; const float* rotations;
    const float* viewmatrix; const float* projmatrix; const float* cam_pos;
    const float* tanfovx; const float* tanfovy;
    const int* width; const int* height; const int* D;
    int M; int P; int npix;
    const float* background;
    float* out; float* ws;
};

// ---------------- phase A body: per-gaussian preprocess ----------------
__device__ void do_preprocess(int p, const GSParams& pr,
                              int Wi, int Hi)
{
    const float W = (float)Wi, H = (float)Hi;
    const float tanfovx = *pr.tanfovx, tanfovy = *pr.tanfovy;
    const float focal_x = W / (2.0f * tanfovx);
    const float focal_y = H / (2.0f * tanfovy);
    const float sm = *pr.scale_mod;
    const int   deg = *pr.D;
    const float* V  = pr.viewmatrix;
    const float* PM = pr.projmatrix;
    float* ws = pr.ws;
    int P = pr.P, npix = pr.npix, M = pr.M;

    float mx = pr.means3D[3*p+0], my = pr.means3D[3*p+1], mz = pr.means3D[3*p+2];

    float pvx = mx*V[0] + my*V[4] + mz*V[8]  + V[12];
    float pvy = mx*V[1] + my*V[5] + mz*V[9]  + V[13];
    float pvz = mx*V[2] + my*V[6] + mz*V[10] + V[14];
    float depth = pvz;

    float ph0 = mx*PM[0] + my*PM[4] + mz*PM[8]  + PM[12];
    float ph1 = mx*PM[1] + my*PM[5] + mz*PM[9]  + PM[13];
    float ph3 = mx*PM[3] + my*PM[7] + mz*PM[11] + PM[15];
    float ppx = ph0 / (ph3 + 1e-7f);
    float ppy = ph1 / (ph3 + 1e-7f);

    float qw = pr.rotations[4*p+0], qx = pr.rotations[4*p+1],
          qy = pr.rotations[4*p+2], qz = pr.rotations[4*p+3];
    float qn = sqrtf(qw*qw + qx*qx + qy*qy + qz*qz);
    qw /= qn; qx /= qn; qy /= qn; qz /= qn;
    float R00 = 1.f - 2.f*(qy*qy + qz*qz), R01 = 2.f*(qx*qy - qw*qz), R02 = 2.f*(qx*qz + qw*qy);
    float R10 = 2.f*(qx*qy + qw*qz), R11 = 1.f - 2.f*(qx*qx + qz*qz), R12 = 2.f*(qy*qz - qw*qx);
    float R20 = 2.f*(qx*qz - qw*qy), R21 = 2.f*(qy*qz + qw*qx), R22 = 1.f - 2.f*(qx*qx + qy*qy);

    float S0 = pr.scales[3*p+0]*sm, S1 = pr.scales[3*p+1]*sm, S2 = pr.scales[3*p+2]*sm;
    float a0 = R00*S0, a1 = R01*S1, a2 = R02*S2;
    float b0 = R10*S0, b1 = R11*S1, b2 = R12*S2;
    float c0 = R20*S0, c1 = R21*S1, c2 = R22*S2;
    float s00 = a0*a0 + a1*a1 + a2*a2;
    float s01 = a0*b0 + a1*b1 + a2*b2;
    float s02 = a0*c0 + a1*c1 + a2*c2;
    float s11 = b0*b0 + b1*b1 + b2*b2;
    float s12 = b0*c0 + b1*c1 + b2*c2;
    float s22 = c0*c0 + c1*c1 + c2*c2;

    float tx = pvx, ty = pvy, tz = pvz;
    tz = (fabsf(tz) < 1e-6f) ? 1e-6f : tz;
    float limx = 1.3f * tanfovx, limy = 1.3f * tanfovy;
    tx = fminf(fmaxf(tx / tz, -limx), limx) * tz;
    ty = fminf(fmaxf(ty / tz, -limy), limy) * tz;
    float J00 = focal_x / tz;
    float J02 = -focal_x * tx / (tz * tz);
    float J11 = focal_y / tz;
    float J12 = -focal_y * ty / (tz * tz);

    float t00 = J00*V[0*4+0] + J02*V[0*4+2];
    float t01 = J00*V[1*4+0] + J02*V[1*4+2];
    float t02 = J00*V[2*4+0] + J02*V[2*4+2];
    float t10 = J11*V[0*4+1] + J12*V[0*4+2];
    float t11 = J11*V[1*4+1] + J12*V[1*4+2];
    float t12 = J11*V[2*4+1] + J12*V[2*4+2];

    float m00 = t00*s00 + t01*s01 + t02*s02;
    float m01 = t00*s01 + t01*s11 + t02*s12;
    float m02 = t00*s02 + t01*s12 + t02*s22;
    float m10 = t10*s00 + t11*s01 + t12*s02;
    float m11 = t10*s01 + t11*s11 + t12*s12;
    float m12 = t10*s02 + t11*s12 + t12*s22;
    float cov00 = m00*t00 + m01*t01 + m02*t02;
    float cov01 = m00*t10 + m01*t11 + m02*t12;
    float cov11 = m10*t10 + m11*t11 + m12*t12;

    float aa = cov00 + 0.3f;
    float cc = cov11 + 0.3f;
    float bb = cov01;
    float det = aa*cc - bb*bb;
    float det_s = (det == 0.0f) ? 1.0f : det;
    float conA =  cc / det_s;
    float conB = -bb / det_s;
    float conC =  aa / det_s;
    float mid  = 0.5f * (aa + cc);
    float disc = sqrtf(fmaxf(0.1f, mid*mid - det));
    float radius = ceilf(3.0f * sqrtf(fmaxf(mid + disc, mid - disc)));

    float xi = ((ppx + 1.0f) * W - 1.0f) * 0.5f;
    float yi = ((ppy + 1.0f) * H - 1.0f) * 0.5f;

    bool vis = (depth > 0.2f) && (det != 0.0f) && (radius > 0.0f);

    pr.out[4*npix + p]     = vis ? radius : 0.0f;
    pr.out[4*npix + P + p] = vis ? 1.0f : 0.0f;

    // SH -> rgb
    float dx0 = mx - pr.cam_pos[0], dy0 = my - pr.cam_pos[1], dz0 = mz - pr.cam_pos[2];
    float dn = sqrtf(dx0*dx0 + dy0*dy0 + dz0*dz0);
    float x = dx0/dn, y = dy0/dn, z = dz0/dn;
    float xx = x*x, yy = y*y, zz = z*z;
    float xy = x*y, yz = y*z, xz = x*z;
    const float* shb = pr.shs + (size_t)p * M * 3;
    float rgb[3];
    #pragma unroll
    for (int ch = 0; ch < 3; ++ch) {
        float r = 0.28209479177387814f * shb[0*3+ch];
        if (deg >= 1) {
            r = r - 0.4886025119029199f * y * shb[1*3+ch]
                  + 0.4886025119029199f * z * shb[2*3+ch]
                  - 0.4886025119029199f * x * shb[3*3+ch];
        }
        if (deg >= 2) {
            r = r + 1.0925484305920792f  * xy * shb[4*3+ch]
                  + (-1.0925484305920792f) * yz * shb[5*3+ch]
                  + 0.31539156525252005f * (2.0f*zz - xx - yy) * shb[6*3+ch]
                  + (-1.0925484305920792f) * xz * shb[7*3+ch]
                  + 0.5462742152960396f  * (xx - yy) * shb[8*3+ch];
        }
        if (deg >= 3) {
            r = r + (-0.5900435899266435f) * y * (3.0f*xx - yy) * shb[9*3+ch]
                  + 2.890611442640554f   * xy * z * shb[10*3+ch]
                  + (-0.4570457994644658f) * y * (4.0f*zz - xx - yy) * shb[11*3+ch]
                  + 0.3731763325901154f  * z * (2.0f*zz - 3.0f*xx - 3.0f*yy) * shb[12*3+ch]
                  + (-0.4570457994644658f) * x * (4.0f*zz - xx - yy) * shb[13*3+ch]
                  + 1.445305721320277f   * z * (xx - yy) * shb[14*3+ch]
                  + (-0.5900435899266435f) * x * (xx - 3.0f*yy) * shb[15*3+ch];
        }
        rgb[ch] = fmaxf(r + 0.5f, 0.0f);
    }

    float key = vis ? depth : f_inf();
    float opa = pr.opacities[p];

    // exact cull ellipse: alpha >= 1/255  <=>  d' Sigma^-1 d <= K = 2 ln(255*opa)
    float K = 2.0f * logf(255.0f * opa);
    float ex = -1.0f, ey = -1.0f;
    if (vis && K > 0.0f) {
        ex = sqrtf(K * aa) * 1.00002f + 1e-3f;
        ey = sqrtf(K * cc) * 1.00002f + 1e-3f;
    }

    float4* u0 = (float4*)(ws + WS_U0);
    float4* u1 = (float4*)(ws + WS_U1);
    float4* u2 = (float4*)(ws + WS_U2);
    float4* ub = (float4*)(ws + WS_UB);
    u0[p] = make_float4(xi, yi, conA, conB);
    u1[p] = make_float4(conC, opa, depth, key);
    u2[p] = make_float4(rgb[0], rgb[1], rgb[2], 0.0f);
    ub[p] = make_float4(xi, yi, ex, ey);
    ws[WS_KEY + p] = key;
}

// ---------------- fused cooperative kernel ----------------
__global__ __launch_bounds__(NT) void gs_fused(GSParams pr)
{
    cg::grid_group grid = cg::this_grid();

    float* ws = pr.ws;
    const int P = pr.P, npix = pr.npix;
    const int Wi = *pr.width, Hi = *pr.height;
    const int ntx = (Wi + 7) >> 3, nty = (Hi + 7) >> 3;
    const int ntiles = ntx * nty;

    const int gtid = blockIdx.x * NT + threadIdx.x;
    const int lane = threadIdx.x & 63;
    const int wib  = threadIdx.x >> 6;          // wave in block (0..3)
    const int gwv  = (blockIdx.x * NT + threadIdx.x) >> 6;  // global wave id

    // ================= phase A: zero masks + preprocess =================
    {
        int nwords = ntiles * 32;
        unsigned long long* mask = (unsigned long long*)(ws + WS_MASK);
        for (int i = gtid; i < nwords; i += NB * NT) mask[i] = 0ull;
        if (gtid < P) do_preprocess(gtid, pr, Wi, Hi);
    }

    grid.sync();

    // ================= phase B: wave-per-gaussian rank + scatter + tile bits =================
    {
        const float* keys = ws + WS_KEY;
        const float4* k4 = (const float4*)keys;
        // hoist the whole key array into registers (64 lanes x 8 float4 = 2048 keys)
        float4 kq[NSORT / 256];
        #pragma unroll
        for (int i = 0; i < NSORT / 256; ++i) kq[i] = k4[(i << 6) | lane];

        const float4* u0 = (const float4*)(ws + WS_U0);
        const float4* u1 = (const float4*)(ws + WS_U1);
        const float4* u2 = (const float4*)(ws + WS_U2);
        const float4* ub = (const float4*)(ws + WS_UB);
        float4* s0 = (float4*)(ws + WS_S0);
        float4* s1 = (float4*)(ws + WS_S1);
        float4* s2 = (float4*)(ws + WS_S2);
        float4* sb = (float4*)(ws + WS_SB);
        unsigned long long* mask = (unsigned long long*)(ws + WS_MASK);

        for (int p = gwv; p < P; p += NWAVES) {
            float kp = keys[p];                  // wave-uniform broadcast
            int rank = 0;
            #pragma unroll
            for (int i = 0; i < NSORT / 256; ++i) {
                int q = ((i << 6) | lane) << 2;
                rank += (q+0 < P) && ((kq[i].x < kp) || (kq[i].x == kp && (q+0) < p));
                rank += (q+1 < P) && ((kq[i].y < kp) || (kq[i].y == kp && (q+1) < p));
                rank += (q+2 < P) && ((kq[i].z < kp) || (kq[i].z == kp && (q+2) < p));
                rank += (q+3 < P) && ((kq[i].w < kp) || (kq[i].w == kp && (q+3) < p));
            }
            #pragma unroll
            for (int d = 32; d >= 1; d >>= 1) rank += __shfl_xor(rank, d);

            if      (lane == 0) s0[rank] = u0[p];
            else if (lane == 1) s1[rank] = u1[p];
            else if (lane == 2) s2[rank] = u2[p];
            else if (lane == 3) sb[rank] = ub[p];

            float4 b = ub[p];                    // wave-uniform
            if (b.z < 0.0f) continue;

            int txl = max(0, (int)floorf((b.x - b.z - 7.0f) * 0.125f) - 1);
            int txh = min(ntx - 1, (int)floorf((b.x + b.z) * 0.125f) + 1);
            int tyl = max(0, (int)floorf((b.y - b.w - 7.0f) * 0.125f) - 1);
            int tyh = min(nty - 1, (int)floorf((b.y + b.w) * 0.125f) + 1);
            int spanx = txh - txl + 1;
            int total = spanx * (tyh - tyl + 1);
            if (total <= 0) continue;

            unsigned long long bit = 1ull << (rank & 63);
            int word = rank >> 6;

            for (int s = lane; s < total; s += 64) {
                int tx = txl + (s % spanx);
                int ty = tyl + (s / spanx);
                float x0 = (float)(tx << 3);
                float x1 = (float)min((tx << 3) + 7, Wi - 1);
                float y0 = (float)(ty << 3);
                float y1 = (float)min((ty << 3) + 7, Hi - 1);
                bool hit = (b.x + b.z >= x0) && (b.x - b.z <= x1) &&
                           (b.y + b.w >= y0) && (b.y - b.w <= y1);
                if (hit) atomicOr(&mask[(tx * nty + ty) * 32 + word], bit);
            }
        }
    }

    grid.sync();

    // ================= phase C: wave-per-tile render (wave-synchronous) =================
    {
        const float4* s0 = (const float4*)(ws + WS_S0);
        const float4* s1 = (const float4*)(ws + WS_S1);
        const float4* s2 = (const float4*)(ws + WS_S2);
        const unsigned long long* mask = (const unsigned long long*)(ws + WS_MASK);
        float bg0 = pr.background[0], bg1 = pr.background[1], bg2 = pr.background[2];
        float* out = pr.out;

        __shared__ unsigned short list[NT/64][NSORT];
        __shared__ float4 st0[NT/64][64], st1[NT/64][64], st2[NT/64][64];

        for (int t = gwv; t < ntiles; t += NWAVES) {
            int tx = t / nty, ty = t - tx * nty;
            int x = (tx << 3) + (lane >> 3);
            int y = (ty << 3) + (lane & 7);
            bool inimg = (x < Wi) && (y < Hi);
            float fx = (float)x, fy = (float)y;

            // ---- build compacted sorted-index list from the 32 mask words ----
            unsigned long long m = (lane < 32) ? mask[t * 32 + lane] : 0ull;
            int c = __popcll(m);
            int inc = c;
            #pragma unroll
            for (int d = 1; d < 32; d <<= 1) {
                int v = __shfl_up(inc, d);
                if (lane >= d) inc += v;
            }
            int off = inc - c;                    // exclusive prefix (lanes 0..31)
            int nl = __shfl(inc, 31);             // total
            unsigned short* lst = list[wib];
            if (lane < 32) {
                int base = lane << 6;
                int o = off;
                while (m) {
                    int k = __ffsll(m) - 1;
                    m &= (m - 1);
                    lst[o++] = (unsigned short)(base + k);
                }
            }

            float T = 1.0f, Tf = 1.0f;
            float cr = 0.0f, cg_ = 0.0f, cb = 0.0f, da = 0.0f;
            bool done = !inimg;

            float4 r0, r1, r2;
            if (lane < nl) {
                int g = lst[lane];
                r0 = s0[g]; r1 = s1[g]; r2 = s2[g];
            }

            for (int base = 0; base < nl; base += 64) {
                int n = min(64, nl - base);
                if (lane < n) { st0[wib][lane] = r0; st1[wib][lane] = r1; st2[wib][lane] = r2; }
                int nb2 = base + 64;
                if (nb2 + lane < nl) {
                    int g = lst[nb2 + lane];
                    r0 = s0[g]; r1 = s1[g]; r2 = s2[g];
                }
                for (int e = 0; e < n; ++e) {
                    float4 a0 = st0[wib][e];
                    float4 a1 = st1[wib][e];
                    float4 a2 = st2[wib][e];
                    if (!done) {
                        float dx = a0.x - fx, dy = a0.y - fy;
                        float power = -0.5f * (a0.z * dx * dx + a1.x * dy * dy) - a0.w * dx * dy;
                        if (power <= 0.0f) {
                            float alpha = fminf(0.99f, a1.y * __expf(power));
                            if (alpha >= (1.0f / 255.0f)) {
                                float Tn = T * (1.0f - alpha);
                                if (Tn < 1e-4f) {
                                    done = true;
                                } else {
                                    float wg = alpha * T;
                                    cr += wg * a2.x; cg_ += wg * a2.y; cb += wg * a2.z;
                                    da += wg * a1.z;
                                    T = Tn; Tf = Tn;
                                }
                            }
                        }
                    }
                }
                if (__all(done)) break;
            }

            if (inimg) {
                int p = x * Hi + y;
                out[3*p + 0] = cr + Tf * bg0;
                out[3*p + 1] = cg_ + Tf * bg1;
                out[3*p + 2] = cb + Tf * bg2;
                out[3*npix + p] = da;
            }
        }
    }
}

extern "C" void kernel_launch(void* const* d_in, const int* in_sizes, int n_in,
                              void* d_out, int out_size, void* d_ws, size_t ws_size,
                              hipStream_t stream) {
    GSParams pr;
    pr.D          = (const int*)d_in[1];
    pr.background = (const float*)d_in[3];
    pr.width      = (const int*)d_in[4];
    pr.height     = (const int*)d_in[5];
    pr.means3D    = (const float*)d_in[6];
    pr.shs        = (const float*)d_in[7];
    pr.opacities  = (const float*)d_in[8];
    pr.scales     = (const float*)d_in[9];
    pr.scale_mod  = (const float*)d_in[10];
    pr.rotations  = (const float*)d_in[11];
    pr.viewmatrix = (const float*)d_in[12];
    pr.projmatrix = (const float*)d_in[13];
    pr.cam_pos    = (const float*)d_in[14];
    pr.tanfovx    = (const float*)d_in[15];
    pr.tanfovy    = (const float*)d_in[16];

    pr.P    = in_sizes[6] / 3;
    pr.M    = in_sizes[7] / (pr.P * 3);
    pr.npix = (out_size - 2 * pr.P) / 4;   // width*height
    pr.out  = (float*)d_out;
    pr.ws   = (float*)d_ws;

    void* args[] = { &pr };
    hipLaunchCooperativeKernel((const void*)gs_fused, dim3(NB), dim3(NT),
                               args, 0, stream);
}

// Round 6
// 43.319 us; speedup vs baseline: 2.6040x; 2.6040x over previous
//
#include <hip/hip_runtime.h>
#include <math.h>

// ---------------- workspace layout (in floats) ----------------
#define NSORT 2048
#define WS_U0   0                 // unsorted (xi, yi, conA, conB)
#define WS_U1   (NSORT*4)         // unsorted (conC, opa, depth, key)
#define WS_U2   (NSORT*8)         // unsorted (r, g, b, 0)
#define WS_UB   (NSORT*12)        // unsorted bbox (xc, yc, ex, ey); ex<0 => never contributes
#define WS_KEY  (NSORT*16)
#define WS_S0   (NSORT*17)        // depth-sorted copies
#define WS_S1   (NSORT*21)
#define WS_S2   (NSORT*25)
#define WS_SB   (NSORT*29)
#define WS_MASK (NSORT*33)        // u64 masks: ntiles x 32 words (8-byte aligned)

__device__ __forceinline__ float f_inf() { return __int_as_float(0x7f800000); }

// ---------------- kernel 1: per-gaussian preprocess (+ zero tile masks) ----------------
// 64-thread blocks: spreads the 2048 long-dependency-chain threads over 32 CUs.
__global__ __launch_bounds__(64) void gs_preprocess(
    const float* __restrict__ means3D, const float* __restrict__ shs,
    const float* __restrict__ opacities, const float* __restrict__ scales,
    const float* __restrict__ scale_mod_p, const float* __restrict__ rotations,
    const float* __restrict__ viewmatrix, const float* __restrict__ projmatrix,
    const float* __restrict__ cam_pos,
    const float* __restrict__ tanfovx_p, const float* __restrict__ tanfovy_p,
    const int* __restrict__ width_p, const int* __restrict__ height_p,
    const int* __restrict__ D_p, int M, int P, int npix,
    float* __restrict__ out, float* __restrict__ ws)
{
    int p = blockIdx.x * blockDim.x + threadIdx.x;

    const int Wi = *width_p, Hi = *height_p;
    // zero tile bitmask words (grid-stride)
    {
        int ntx = (Wi + 7) >> 3, nty = (Hi + 7) >> 3;
        int nwords = ntx * nty * 32;
        unsigned long long* mask = (unsigned long long*)(ws + WS_MASK);
        for (int i = p; i < nwords; i += gridDim.x * blockDim.x) mask[i] = 0ull;
    }
    if (p >= P) return;

    const float W = (float)Wi, H = (float)Hi;
    const float tanfovx = *tanfovx_p, tanfovy = *tanfovy_p;
    const float focal_x = W / (2.0f * tanfovx);
    const float focal_y = H / (2.0f * tanfovy);
    const float sm = *scale_mod_p;
    const int   deg = *D_p;
    const float* V  = viewmatrix;
    const float* PM = projmatrix;

    float mx = means3D[3*p+0], my = means3D[3*p+1], mz = means3D[3*p+2];

    float pvx = mx*V[0] + my*V[4] + mz*V[8]  + V[12];
    float pvy = mx*V[1] + my*V[5] + mz*V[9]  + V[13];
    float pvz = mx*V[2] + my*V[6] + mz*V[10] + V[14];
    float depth = pvz;

    float ph0 = mx*PM[0] + my*PM[4] + mz*PM[8]  + PM[12];
    float ph1 = mx*PM[1] + my*PM[5] + mz*PM[9]  + PM[13];
    float ph3 = mx*PM[3] + my*PM[7] + mz*PM[11] + PM[15];
    float ppx = ph0 / (ph3 + 1e-7f);
    float ppy = ph1 / (ph3 + 1e-7f);

    float qw = rotations[4*p+0], qx = rotations[4*p+1],
          qy = rotations[4*p+2], qz = rotations[4*p+3];
    float qn = sqrtf(qw*qw + qx*qx + qy*qy + qz*qz);
    qw /= qn; qx /= qn; qy /= qn; qz /= qn;
    float R00 = 1.f - 2.f*(qy*qy + qz*qz), R01 = 2.f*(qx*qy - qw*qz), R02 = 2.f*(qx*qz + qw*qy);
    float R10 = 2.f*(qx*qy + qw*qz), R11 = 1.f - 2.f*(qx*qx + qz*qz), R12 = 2.f*(qy*qz - qw*qx);
    float R20 = 2.f*(qx*qz - qw*qy), R21 = 2.f*(qy*qz + qw*qx), R22 = 1.f - 2.f*(qx*qx + qy*qy);

    float S0 = scales[3*p+0]*sm, S1 = scales[3*p+1]*sm, S2 = scales[3*p+2]*sm;
    float a0 = R00*S0, a1 = R01*S1, a2 = R02*S2;
    float b0 = R10*S0, b1 = R11*S1, b2 = R12*S2;
    float c0 = R20*S0, c1 = R21*S1, c2 = R22*S2;
    float s00 = a0*a0 + a1*a1 + a2*a2;
    float s01 = a0*b0 + a1*b1 + a2*b2;
    float s02 = a0*c0 + a1*c1 + a2*c2;
    float s11 = b0*b0 + b1*b1 + b2*b2;
    float s12 = b0*c0 + b1*c1 + b2*c2;
    float s22 = c0*c0 + c1*c1 + c2*c2;

    float tx = pvx, ty = pvy, tz = pvz;
    tz = (fabsf(tz) < 1e-6f) ? 1e-6f : tz;
    float limx = 1.3f * tanfovx, limy = 1.3f * tanfovy;
    tx = fminf(fmaxf(tx / tz, -limx), limx) * tz;
    ty = fminf(fmaxf(ty / tz, -limy), limy) * tz;
    float J00 = focal_x / tz;
    float J02 = -focal_x * tx / (tz * tz);
    float J11 = focal_y / tz;
    float J12 = -focal_y * ty / (tz * tz);

    float t00 = J00*V[0*4+0] + J02*V[0*4+2];
    float t01 = J00*V[1*4+0] + J02*V[1*4+2];
    float t02 = J00*V[2*4+0] + J02*V[2*4+2];
    float t10 = J11*V[0*4+1] + J12*V[0*4+2];
    float t11 = J11*V[1*4+1] + J12*V[1*4+2];
    float t12 = J11*V[2*4+1] + J12*V[2*4+2];

    float m00 = t00*s00 + t01*s01 + t02*s02;
    float m01 = t00*s01 + t01*s11 + t02*s12;
    float m02 = t00*s02 + t01*s12 + t02*s22;
    float m10 = t10*s00 + t11*s01 + t12*s02;
    float m11 = t10*s01 + t11*s11 + t12*s12;
    float m12 = t10*s02 + t11*s12 + t12*s22;
    float cov00 = m00*t00 + m01*t01 + m02*t02;
    float cov01 = m00*t10 + m01*t11 + m02*t12;
    float cov11 = m10*t10 + m11*t11 + m12*t12;

    float aa = cov00 + 0.3f;
    float cc = cov11 + 0.3f;
    float bb = cov01;
    float det = aa*cc - bb*bb;
    float det_s = (det == 0.0f) ? 1.0f : det;
    float conA =  cc / det_s;
    float conB = -bb / det_s;
    float conC =  aa / det_s;
    float mid  = 0.5f * (aa + cc);
    float disc = sqrtf(fmaxf(0.1f, mid*mid - det));
    float radius = ceilf(3.0f * sqrtf(fmaxf(mid + disc, mid - disc)));

    float xi = ((ppx + 1.0f) * W - 1.0f) * 0.5f;
    float yi = ((ppy + 1.0f) * H - 1.0f) * 0.5f;

    bool vis = (depth > 0.2f) && (det != 0.0f) && (radius > 0.0f);

    out[4*npix + p]     = vis ? radius : 0.0f;
    out[4*npix + P + p] = vis ? 1.0f : 0.0f;

    // SH -> rgb
    float dx0 = mx - cam_pos[0], dy0 = my - cam_pos[1], dz0 = mz - cam_pos[2];
    float dn = sqrtf(dx0*dx0 + dy0*dy0 + dz0*dz0);
    float x = dx0/dn, y = dy0/dn, z = dz0/dn;
    float xx = x*x, yy = y*y, zz = z*z;
    float xy = x*y, yz = y*z, xz = x*z;
    const float* shb = shs + (size_t)p * M * 3;
    float rgb[3];
    #pragma unroll
    for (int ch = 0; ch < 3; ++ch) {
        float r = 0.28209479177387814f * shb[0*3+ch];
        if (deg >= 1) {
            r = r - 0.4886025119029199f * y * shb[1*3+ch]
                  + 0.4886025119029199f * z * shb[2*3+ch]
                  - 0.4886025119029199f * x * shb[3*3+ch];
        }
        if (deg >= 2) {
            r = r + 1.0925484305920792f  * xy * shb[4*3+ch]
                  + (-1.0925484305920792f) * yz * shb[5*3+ch]
                  + 0.31539156525252005f * (2.0f*zz - xx - yy) * shb[6*3+ch]
                  + (-1.0925484305920792f) * xz * shb[7*3+ch]
                  + 0.5462742152960396f  * (xx - yy) * shb[8*3+ch];
        }
        if (deg >= 3) {
            r = r + (-0.5900435899266435f) * y * (3.0f*xx - yy) * shb[9*3+ch]
                  + 2.890611442640554f   * xy * z * shb[10*3+ch]
                  + (-0.4570457994644658f) * y * (4.0f*zz - xx - yy) * shb[11*3+ch]
                  + 0.3731763325901154f  * z * (2.0f*zz - 3.0f*xx - 3.0f*yy) * shb[12*3+ch]
                  + (-0.4570457994644658f) * x * (4.0f*zz - xx - yy) * shb[13*3+ch]
                  + 1.445305721320277f   * z * (xx - yy) * shb[14*3+ch]
                  + (-0.5900435899266435f) * x * (xx - 3.0f*yy) * shb[15*3+ch];
        }
        rgb[ch] = fmaxf(r + 0.5f, 0.0f);
    }

    float key = vis ? depth : f_inf();
    float opa = opacities[p];

    // exact cull ellipse: alpha >= 1/255  <=>  d' Sigma^-1 d <= K = 2 ln(255*opa)
    float K = 2.0f * logf(255.0f * opa);
    float ex = -1.0f, ey = -1.0f;
    if (vis && K > 0.0f) {
        ex = sqrtf(K * aa) * 1.00002f + 1e-3f;
        ey = sqrtf(K * cc) * 1.00002f + 1e-3f;
    }

    float4* u0 = (float4*)(ws + WS_U0);
    float4* u1 = (float4*)(ws + WS_U1);
    float4* u2 = (float4*)(ws + WS_U2);
    float4* ub = (float4*)(ws + WS_UB);
    u0[p] = make_float4(xi, yi, conA, conB);
    u1[p] = make_float4(conC, opa, depth, key);
    u2[p] = make_float4(rgb[0], rgb[1], rgb[2], 0.0f);
    ub[p] = make_float4(xi, yi, ex, ey);
    ws[WS_KEY + p] = key;
}

// ---------------- kernel 2: wave-per-gaussian rank + scatter + tile bitmask ----------------
__global__ __launch_bounds__(256) void gs_rank(
    float* __restrict__ ws,
    const int* __restrict__ width_p, const int* __restrict__ height_p, int P)
{
    int gtid = blockIdx.x * blockDim.x + threadIdx.x;
    int p = gtid >> 6;
    int lane = threadIdx.x & 63;
    if (p >= P) return;

    const float* keys = ws + WS_KEY;
    float kp = keys[p];                       // wave-uniform broadcast

    const float4* k4 = (const float4*)keys;
    int rank = 0;
    #pragma unroll
    for (int i = 0; i < NSORT / 256; ++i) {   // 8 iterations, 64 lanes x float4 = 256 keys each
        int q4 = (i << 6) | lane;
        float4 kq = k4[q4];
        int q = q4 << 2;
        rank += (q+0 < P) && ((kq.x < kp) || (kq.x == kp && (q+0) < p));
        rank += (q+1 < P) && ((kq.y < kp) || (kq.y == kp && (q+1) < p));
        rank += (q+2 < P) && ((kq.z < kp) || (kq.z == kp && (q+2) < p));
        rank += (q+3 < P) && ((kq.w < kp) || (kq.w == kp && (q+3) < p));
    }
    #pragma unroll
    for (int d = 32; d >= 1; d >>= 1) rank += __shfl_xor(rank, d);

    const float4* u0 = (const float4*)(ws + WS_U0);
    const float4* u1 = (const float4*)(ws + WS_U1);
    const float4* u2 = (const float4*)(ws + WS_U2);
    const float4* ub = (const float4*)(ws + WS_UB);
    float4* s0 = (float4*)(ws + WS_S0);
    float4* s1 = (float4*)(ws + WS_S1);
    float4* s2 = (float4*)(ws + WS_S2);
    float4* sb = (float4*)(ws + WS_SB);

    if      (lane == 0) s0[rank] = u0[p];
    else if (lane == 1) s1[rank] = u1[p];
    else if (lane == 2) s2[rank] = u2[p];
    else if (lane == 3) sb[rank] = ub[p];

    // ---- tile bitmask: bit = rank, lane-parallel over the bbox tile span ----
    float4 b = ub[p];                         // wave-uniform
    if (b.z < 0.0f) return;

    int W = *width_p, H = *height_p;
    int ntx = (W + 7) >> 3, nty = (H + 7) >> 3;

    int txl = max(0, (int)floorf((b.x - b.z - 7.0f) * 0.125f) - 1);
    int txh = min(ntx - 1, (int)floorf((b.x + b.z) * 0.125f) + 1);
    int tyl = max(0, (int)floorf((b.y - b.w - 7.0f) * 0.125f) - 1);
    int tyh = min(nty - 1, (int)floorf((b.y + b.w) * 0.125f) + 1);
    int spanx = txh - txl + 1;
    int spany = tyh - tyl + 1;
    int total = spanx * spany;
    if (total <= 0) return;

    unsigned long long* mask = (unsigned long long*)(ws + WS_MASK);
    unsigned long long bit = 1ull << (rank & 63);
    int word = rank >> 6;

    for (int s = lane; s < total; s += 64) {
        int tx = txl + (s % spanx);
        int ty = tyl + (s / spanx);
        float x0 = (float)(tx << 3);
        float x1 = (float)min((tx << 3) + 7, W - 1);
        float y0 = (float)(ty << 3);
        float y1 = (float)min((ty << 3) + 7, H - 1);
        bool hit = (b.x + b.z >= x0) && (b.x - b.z <= x1) &&
                   (b.y + b.w >= y0) && (b.y - b.w <= y1);
        if (hit) atomicOr(&mask[(tx * nty + ty) * 32 + word], bit);
    }
}

// ---------------- kernel 3: per-tile render, list + LDS chunk staging, 2-way ILP ----------------
__global__ __launch_bounds__(64) void gs_render(
    const float* __restrict__ ws, const float* __restrict__ background,
    const int* __restrict__ width_p, const int* __restrict__ height_p,
    float* __restrict__ out, int npix)
{
    int W = *width_p, H = *height_p;
    int ntx = (W + 7) >> 3, nty = (H + 7) >> 3;
    int ntiles = ntx * nty;

    const float4* s0 = (const float4*)(ws + WS_S0);
    const float4* s1 = (const float4*)(ws + WS_S1);
    const float4* s2 = (const float4*)(ws + WS_S2);
    const unsigned long long* mask = (const unsigned long long*)(ws + WS_MASK);
    float bg0 = background[0], bg1 = background[1], bg2 = background[2];

    __shared__ unsigned short list[NSORT];
    __shared__ float4 st0[64], st1[64], st2[64];

    int tid = threadIdx.x;

    for (int t = blockIdx.x; t < ntiles; t += gridDim.x) {
        int tx = t / nty, ty = t - tx * nty;
        int x = (tx << 3) + (tid >> 3);
        int y = (ty << 3) + (tid & 7);
        bool inimg = (x < W) && (y < H);
        float fx = (float)x, fy = (float)y;

        // ---- build compacted sorted-index list from the 32 mask words ----
        unsigned long long m = (tid < 32) ? mask[t * 32 + tid] : 0ull;
        int c = __popcll(m);
        int inc = c;
        #pragma unroll
        for (int d = 1; d < 32; d <<= 1) {
            int v = __shfl_up(inc, d);
            if (tid >= d) inc += v;
        }
        int off = inc - c;                    // exclusive prefix (lanes 0..31)
        int nlist = __shfl(inc, 31);          // total (valid in all lanes)
        if (tid < 32) {
            int base = tid << 6;
            int o = off;
            while (m) {
                int k = __ffsll(m) - 1;
                m &= (m - 1);
                list[o++] = (unsigned short)(base + k);
            }
        }
        __syncthreads();

        float T = 1.0f, Tf = 1.0f;
        float cr = 0.0f, cg = 0.0f, cb = 0.0f, da = 0.0f;
        bool done = !inimg;

        // preload chunk 0 into registers
        float4 r0, r1, r2;
        if (tid < nlist) {
            int g = list[tid];
            r0 = s0[g]; r1 = s1[g]; r2 = s2[g];
        }

        for (int base = 0; base < nlist; base += 64) {
            int n = min(64, nlist - base);
            if (tid < n) { st0[tid] = r0; st1[tid] = r1; st2[tid] = r2; }
            __syncthreads();
            int nb2 = base + 64;
            if (nb2 + tid < nlist) {
                int g = list[nb2 + tid];
                r0 = s0[g]; r1 = s1[g]; r2 = s2[g];
            }

            // ---- blend: 2 entries per iteration (alpha computed in parallel,
            //      T-update applied sequentially => bit-identical result) ----
            int e = 0;
            for (; e + 1 < n; e += 2) {
                float4 a0A = st0[e],     a1A = st1[e];
                float4 a0B = st0[e + 1], a1B = st1[e + 1];
                float dxA = a0A.x - fx, dyA = a0A.y - fy;
                float dxB = a0B.x - fx, dyB = a0B.y - fy;
                float pwA = -0.5f * (a0A.z * dxA * dxA + a1A.x * dyA * dyA) - a0A.w * dxA * dyA;
                float pwB = -0.5f * (a0B.z * dxB * dxB + a1B.x * dyB * dyB) - a0B.w * dxB * dyB;
                float alA = fminf(0.99f, a1A.y * __expf(pwA));
                float alB = fminf(0.99f, a1B.y * __expf(pwB));
                bool okA = (pwA <= 0.0f) && (alA >= (1.0f / 255.0f));
                bool okB = (pwB <= 0.0f) && (alB >= (1.0f / 255.0f));
                if (!done && okA) {
                    float Tn = T * (1.0f - alA);
                    if (Tn < 1e-4f) done = true;
                    else {
                        float wg = alA * T;
                        float4 a2 = st2[e];
                        cr += wg * a2.x; cg += wg * a2.y; cb += wg * a2.z;
                        da += wg * a1A.z;
                        T = Tn; Tf = Tn;
                    }
                }
                if (!done && okB) {
                    float Tn = T * (1.0f - alB);
                    if (Tn < 1e-4f) done = true;
                    else {
                        float wg = alB * T;
                        float4 a2 = st2[e + 1];
                        cr += wg * a2.x; cg += wg * a2.y; cb += wg * a2.z;
                        da += wg * a1B.z;
                        T = Tn; Tf = Tn;
                    }
                }
                if ((e & 15) == 14 && __all(done)) break;
            }
            if (e < n && !__all(done)) {       // odd tail entry
                float4 a0A = st0[e], a1A = st1[e];
                float dxA = a0A.x - fx, dyA = a0A.y - fy;
                float pwA = -0.5f * (a0A.z * dxA * dxA + a1A.x * dyA * dyA) - a0A.w * dxA * dyA;
                if (!done && pwA <= 0.0f) {
                    float alA = fminf(0.99f, a1A.y * __expf(pwA));
                    if (alA >= (1.0f / 255.0f)) {
                        float Tn = T * (1.0f - alA);
                        if (Tn < 1e-4f) done = true;
                        else {
                            float wg = alA * T;
                            float4 a2 = st2[e];
                            cr += wg * a2.x; cg += wg * a2.y; cb += wg * a2.z;
                            da += wg * a1A.z;
                            T = Tn; Tf = Tn;
                        }
                    }
                }
            }
            __syncthreads();
            if (__all(done)) break;
        }

        if (inimg) {
            int p = x * H + y;
            out[3*p + 0] = cr + Tf * bg0;
            out[3*p + 1] = cg + Tf * bg1;
            out[3*p + 2] = cb + Tf * bg2;
            out[3*npix + p] = da;
        }
        __syncthreads();
    }
}

extern "C" void kernel_launch(void* const* d_in, const int* in_sizes, int n_in,
                              void* d_out, int out_size, void* d_ws, size_t ws_size,
                              hipStream_t stream) {
    const int*   D_p        = (const int*)d_in[1];
    const float* background = (const float*)d_in[3];
    const int*   width_p    = (const int*)d_in[4];
    const int*   height_p   = (const int*)d_in[5];
    const float* means3D    = (const float*)d_in[6];
    const float* shs        = (const float*)d_in[7];
    const float* opacities  = (const float*)d_in[8];
    const float* scales     = (const float*)d_in[9];
    const float* scale_mod  = (const float*)d_in[10];
    const float* rotations  = (const float*)d_in[11];
    const float* viewmatrix = (const float*)d_in[12];
    const float* projmatrix = (const float*)d_in[13];
    const float* cam_pos    = (const float*)d_in[14];
    const float* tanfovx    = (const float*)d_in[15];
    const float* tanfovy    = (const float*)d_in[16];

    int P    = in_sizes[6] / 3;
    int M    = in_sizes[7] / (P * 3);
    int npix = (out_size - 2 * P) / 4;   // width*height
    float* out = (float*)d_out;
    float* ws  = (float*)d_ws;

    gs_preprocess<<<(P + 63) / 64, 64, 0, stream>>>(
        means3D, shs, opacities, scales, scale_mod, rotations,
        viewmatrix, projmatrix, cam_pos, tanfovx, tanfovy,
        width_p, height_p, D_p, M, P, npix, out, ws);

    // one wave per gaussian: P*64 threads
    gs_rank<<<(P * 64 + 255) / 256, 256, 0, stream>>>(ws, width_p, height_p, P);

    gs_render<<<(npix + 63) / 64, 64, 0, stream>>>(
        ws, background, width_p, height_p, out, npix);
}